// Round 7
// baseline (696.806 us; speedup 1.0000x reference)
//
#include <hip/hip_runtime.h>

typedef unsigned short u16;
typedef __bf16 bf16x8 __attribute__((ext_vector_type(8)));
typedef float  f32x4  __attribute__((ext_vector_type(4)));
typedef unsigned short u16x8 __attribute__((ext_vector_type(8)));

union U8cast { u16x8 u; bf16x8 b; };

#define NB 32
#define NN 4096
#define ND 256
#define NS 11
#define NH 256
#define NM 512

__device__ __forceinline__ u16 f2bf(float f) {
  unsigned u = __float_as_uint(f);
  u += 0x7FFF + ((u >> 16) & 1);      // RNE; inputs are finite
  return (u16)(u >> 16);
}
__device__ __forceinline__ float bf2f(u16 h) {
  return __uint_as_float(((unsigned)h) << 16);
}

// ---------------- Wk|Wv -> transposed bf16 wT[512][256] (LDS transpose) ----
__global__ __launch_bounds__(256)
void k_cvt_w(const float* __restrict__ Wk, const float* __restrict__ Wv,
             u16* __restrict__ wT) {
  __shared__ float Lt[64][65];
  int bx = blockIdx.x;              // 32 blocks: 4 k-tiles x 8 c-tiles
  int kt = bx & 3, ct = bx >> 2;
  int k0 = kt * 64, c0 = ct * 64;
  const float* src = (c0 < 256) ? Wk : Wv;
  int c0m = c0 & 255;
  int t = threadIdx.x;
  int kr = t >> 2, part = t & 3;
  const float* sp = src + (size_t)(k0 + kr) * 256 + c0m + part * 16;
#pragma unroll
  for (int g = 0; g < 4; ++g) {
    float4 v = *(const float4*)(sp + g * 4);
    Lt[kr][part*16 + g*4 + 0] = v.x;
    Lt[kr][part*16 + g*4 + 1] = v.y;
    Lt[kr][part*16 + g*4 + 2] = v.z;
    Lt[kr][part*16 + g*4 + 3] = v.w;
  }
  __syncthreads();
  int cr = t >> 2;
  u16* wp = wT + (size_t)(c0 + cr) * 256 + k0 + part * 16;
#pragma unroll
  for (int g = 0; g < 2; ++g) {
    u16x8 o;
#pragma unroll
    for (int j = 0; j < 8; ++j) o[j] = f2bf(Lt[part*16 + g*8 + j][cr]);
    *(u16x8*)(wp + g * 8) = o;
  }
}

// ---------------- convert all small-matmul weights to bf16 -----------------
__global__ void k_cvt_all(const float* __restrict__ Wq, const float* __restrict__ wi,
                          const float* __restrict__ wh, const float* __restrict__ w1,
                          const float* __restrict__ w2, u16* __restrict__ wqb,
                          u16* __restrict__ wib, u16* __restrict__ whb,
                          u16* __restrict__ w1b, u16* __restrict__ w2b) {
  int idx = blockIdx.x * 256 + threadIdx.x;
  if      (idx < 65536)  wqb[idx]          = f2bf(Wq[idx]);
  else if (idx < 262144) wib[idx - 65536]  = f2bf(wi[idx - 65536]);
  else if (idx < 458752) whb[idx - 262144] = f2bf(wh[idx - 262144]);
  else if (idx < 589824) w1b[idx - 458752] = f2bf(w1[idx - 458752]);
  else                   w2b[idx - 589824] = f2bf(w2[idx - 589824]);
}

// ---------------- slots init ----------------------------------------------
__global__ void k_slots_init(const float* __restrict__ noise, const float* __restrict__ mu,
                             const float* __restrict__ ls, float* __restrict__ slots) {
  int row = blockIdx.x, t = threadIdx.x;
  slots[row*256 + t] = mu[t] + expf(ls[t]) * noise[row*256 + t];
}

// ---------------- fused stats + LN + bf16 MFMA GEMM: kv = LN(x) @ [Wk|Wv] --
// Round-4 proven 128x128 tiling (4 blocks/CU, clean writes) + fused per-row
// stats + XCD swizzle: 4096 linear blocks, the 4 col-tiles of each row-tile
// are adjacent on one XCD so x is HBM-fetched ~once per row-tile.
__global__ __launch_bounds__(256)
void k_gemm_kv(const float* __restrict__ x,
               const float* __restrict__ lnsc, const float* __restrict__ lnof,
               const u16* __restrict__ wT, u16* __restrict__ kv) {
  __shared__ __align__(16) u16 Al[128][72];
  __shared__ __align__(16) u16 Bl[128][72];
  __shared__ float scl[256], ofl[256];
  int t = threadIdx.x;
  scl[t] = lnsc[t]; ofl[t] = lnof[t];

  int bid = blockIdx.x;                    // 4096 blocks
  int xcd  = bid & 7;
  int slot = bid >> 3;                     // 0..511 per XCD
  int colt = slot & 3;                     // 4 col-tiles adjacent per row-tile
  int rowt = xcd * 128 + (slot >> 2);      // 0..1023
  int row0 = rowt * 128;
  int col0 = colt * 128;

  // ---- per-row stats: thread pair (2r, 2r+1) scans row r, 128 elems each ----
  int srow = t >> 1, shalf = t & 1;
  const float* xrow = x + (size_t)(row0 + srow) * 256 + shalf * 128;
  float s1 = 0.f, s2 = 0.f;
#pragma unroll
  for (int g = 0; g < 32; ++g) {           // 32 x float4 = 128 elements
    float4 v = *(const float4*)(xrow + g * 4);
    s1 += v.x + v.y + v.z + v.w;
    s2 += v.x*v.x + v.y*v.y + v.z*v.z + v.w*v.w;
  }
  s1 += __shfl_xor(s1, 1);
  s2 += __shfl_xor(s2, 1);
  float mu = s1 * (1.f/256.f);
  float rs = rsqrtf(s2 * (1.f/256.f) - mu*mu + 1e-5f);

  int lane = t & 63, w = t >> 6;
  int wm = (w & 1) * 64, wn = (w >> 1) * 64;
  int fr = lane & 15;
  int kq = (lane >> 4) * 8;
  f32x4 acc[4][4] = {};
  const float* xp0 = x + (size_t)(row0 + srow) * 256 + shalf * 32;
  for (int kc = 0; kc < 256; kc += 64) {
    __syncthreads();
    { // stage A (LN + bf16 cast), 32 elems/thread; reads L1/L2-hot after stats
      const float* xp = xp0 + kc;
#pragma unroll
      for (int g = 0; g < 4; ++g) {
        float4 f0 = *(const float4*)(xp + g*8);
        float4 f1 = *(const float4*)(xp + g*8 + 4);
        int kb = kc + shalf*32 + g*8;
        bf16x8 o;
        o[0] = (__bf16)((f0.x - mu) * (rs * scl[kb+0]) + ofl[kb+0]);
        o[1] = (__bf16)((f0.y - mu) * (rs * scl[kb+1]) + ofl[kb+1]);
        o[2] = (__bf16)((f0.z - mu) * (rs * scl[kb+2]) + ofl[kb+2]);
        o[3] = (__bf16)((f0.w - mu) * (rs * scl[kb+3]) + ofl[kb+3]);
        o[4] = (__bf16)((f1.x - mu) * (rs * scl[kb+4]) + ofl[kb+4]);
        o[5] = (__bf16)((f1.y - mu) * (rs * scl[kb+5]) + ofl[kb+5]);
        o[6] = (__bf16)((f1.z - mu) * (rs * scl[kb+6]) + ofl[kb+6]);
        o[7] = (__bf16)((f1.w - mu) * (rs * scl[kb+7]) + ofl[kb+7]);
        *(bf16x8*)&Al[srow][shalf*32 + g*8] = o;
      }
      const u16* wp = wT + (size_t)(col0 + srow) * 256 + kc + shalf*32;
#pragma unroll
      for (int g = 0; g < 4; ++g)
        *(u16x8*)&Bl[srow][shalf*32 + g*8] = *(const u16x8*)(wp + g*8);
    }
    __syncthreads();
#pragma unroll
    for (int ks = 0; ks < 2; ++ks) {
      int kk = ks*32 + kq;
      bf16x8 af[4], bfr[4];
#pragma unroll
      for (int i = 0; i < 4; ++i) af[i] = *(const bf16x8*)&Al[wm + i*16 + fr][kk];
#pragma unroll
      for (int i = 0; i < 4; ++i) bfr[i] = *(const bf16x8*)&Bl[wn + i*16 + fr][kk];
#pragma unroll
      for (int im = 0; im < 4; ++im)
#pragma unroll
        for (int in = 0; in < 4; ++in)
          acc[im][in] = __builtin_amdgcn_mfma_f32_16x16x32_bf16(af[im], bfr[in], acc[im][in], 0, 0, 0);
    }
  }
  // epilogue: D mapping col=lane&15, row=(lane>>4)*4+r  (round-4 proven)
  int r4 = (lane >> 4) * 4;
#pragma unroll
  for (int im = 0; im < 4; ++im)
#pragma unroll
    for (int in = 0; in < 4; ++in) {
      int gcol = col0 + wn + in*16 + fr;
#pragma unroll
      for (int r = 0; r < 4; ++r) {
        int grow = row0 + wm + im*16 + r4 + r;
        kv[(size_t)grow * 512 + gcol] = f2bf(acc[im][in][r]);
      }
    }
}

// ---------------- q = LN(slots) @ Wq * H^-0.5 (k-split); zero updates ------
__global__ __launch_bounds__(256)
void k_q_ln(const float* __restrict__ slots, const float* __restrict__ sc,
            const float* __restrict__ of, const u16* __restrict__ wqb,
            float* __restrict__ q, float* __restrict__ updates,
            float* __restrict__ colsum) {
  __shared__ float xn[256];
  __shared__ float red[8];
  __shared__ float part[8][256];
  int row = blockIdx.x, t = threadIdx.x;
  float v = slots[row*256 + t];
  float s1 = v, s2 = v*v;
#pragma unroll
  for (int off = 32; off; off >>= 1) { s1 += __shfl_xor(s1, off); s2 += __shfl_xor(s2, off); }
  int w = t >> 6;
  if ((t & 63) == 0) { red[w*2] = s1; red[w*2+1] = s2; }
  __syncthreads();
  float a1 = red[0] + red[2] + red[4] + red[6];
  float a2 = red[1] + red[3] + red[5] + red[7];
  float mu = a1 * (1.f/256.f);
  float rs = rsqrtf(a2 * (1.f/256.f) - mu*mu + 1e-5f);
  xn[t] = (v - mu) * rs * sc[t] + of[t];
  updates[row*256 + t] = 0.f;
  if (t == 0) colsum[(row/11)*16 + (row%11)] = 0.f;
  __syncthreads();
  int tc = t & 31, kg = t >> 5;
  float a[8] = {};
#pragma unroll 8
  for (int kk = 0; kk < 32; ++kk) {
    int k = kg*32 + kk;
    float xv = xn[k];
    u16x8 wv = *(const u16x8*)(wqb + k*256 + tc*8);
#pragma unroll
    for (int j = 0; j < 8; ++j) a[j] += xv * bf2f(wv[j]);
  }
  *(float4*)&part[kg][tc*8]     = make_float4(a[0], a[1], a[2], a[3]);
  *(float4*)&part[kg][tc*8 + 4] = make_float4(a[4], a[5], a[6], a[7]);
  __syncthreads();
  float s = 0.f;
#pragma unroll
  for (int g = 0; g < 8; ++g) s += part[g][t];
  q[row*256 + t] = s * 0.0625f;
}

// ---------------- FUSED attn: logits->softmax->P, updates += P^T @ vf ------
__global__ __launch_bounds__(256)
void k_attn_up(const u16* __restrict__ kv, const float* __restrict__ qg,
               float* __restrict__ updates, float* __restrict__ colsum) {
  __shared__ __align__(16) u16 kfL[64][264];
  __shared__ __align__(16) u16 vfL[64][256];   // chunk-swizzled: col = h ^ (((n>>3)&3)*16)
  __shared__ __align__(16) u16 qTL[16][264];
  __shared__ __align__(16) u16 PTL[16][72];
  __shared__ float Lg[64][17];
  int t = threadIdx.x;
  int b = blockIdx.y;
  int nb0 = blockIdx.x * 256;
  int lane = t & 63, w = t >> 6;
  int fr = lane & 15, kq = lane >> 4;

#pragma unroll
  for (int i = t; i < 512; i += 256) {
    int s = i >> 5, k0 = (i & 31) * 8;
    u16x8 o;
    if (s < 11) {
      const float* qp = qg + (size_t)b*2816 + s*256 + k0;
#pragma unroll
      for (int j = 0; j < 8; ++j) o[j] = f2bf(qp[j]);
    } else {
#pragma unroll
      for (int j = 0; j < 8; ++j) o[j] = 0;
    }
    *(u16x8*)&qTL[s][k0] = o;
  }
  for (int i = t; i < 16*72; i += 256) ((u16*)PTL)[i] = 0;

  f32x4 accU[4] = {};
  float csA[11];
#pragma unroll
  for (int s = 0; s < 11; ++s) csA[s] = 0.f;

  for (int c = 0; c < 4; ++c) {
    int n0 = nb0 + c*64;
    __syncthreads();
    {
      int hc = (t & 31) * 8;
#pragma unroll
      for (int nr = 0; nr < 8; ++nr) {
        int n = nr*8 + (t >> 5);
        size_t base = ((size_t)b*4096 + n0 + n) * 512;
        u16x8 kvk = *(const u16x8*)(kv + base + hc);
        *(u16x8*)&kfL[n][hc] = kvk;
        u16x8 kvv = *(const u16x8*)(kv + base + 256 + hc);
        *(u16x8*)&vfL[n][hc ^ (((n >> 3) & 3) * 16)] = kvv;
      }
    }
    __syncthreads();
    {
      f32x4 aL = {};
#pragma unroll
      for (int kc = 0; kc < 256; kc += 32) {
        bf16x8 af = *(const bf16x8*)&kfL[w*16 + fr][kc + kq*8];
        bf16x8 bq = *(const bf16x8*)&qTL[fr][kc + kq*8];
        aL = __builtin_amdgcn_mfma_f32_16x16x32_bf16(af, bq, aL, 0, 0, 0);
      }
#pragma unroll
      for (int r = 0; r < 4; ++r)
        Lg[w*16 + kq*4 + r][fr] = aL[r];
    }
    __syncthreads();
    if (t < 64) {
      float p[11];
#pragma unroll
      for (int s = 0; s < 11; ++s) p[s] = Lg[t][s];
      float m = p[0];
#pragma unroll
      for (int s = 1; s < 11; ++s) m = fmaxf(m, p[s]);
      float Z = 0.f;
#pragma unroll
      for (int s = 0; s < 11; ++s) { p[s] = __expf(p[s] - m); Z += p[s]; }
      float iz = 1.f / Z;
#pragma unroll
      for (int s = 0; s < 11; ++s) {
        u16 pb = f2bf(p[s]*iz + 1e-8f);
        csA[s] += bf2f(pb);
        PTL[s][t] = pb;
      }
    }
    __syncthreads();
#pragma unroll
    for (int ht = 0; ht < 4; ++ht) {
      int h = w*64 + ht*16 + fr;
#pragma unroll
      for (int kc = 0; kc < 64; kc += 32) {
        bf16x8 aP = *(const bf16x8*)&PTL[fr][kc + kq*8];
        U8cast bv;
#pragma unroll
        for (int j = 0; j < 8; ++j) {
          int k = kc + kq*8 + j;
          bv.u[j] = vfL[k][h ^ (((k >> 3) & 3) * 16)];
        }
        accU[ht] = __builtin_amdgcn_mfma_f32_16x16x32_bf16(aP, bv.b, accU[ht], 0, 0, 0);
      }
    }
  }
#pragma unroll
  for (int ht = 0; ht < 4; ++ht) {
    int h = w*64 + ht*16 + fr;
#pragma unroll
    for (int r = 0; r < 4; ++r) {
      int s = kq*4 + r;
      if (s < 11)
        atomicAdd(&updates[((size_t)b*11 + s)*256 + h], accU[ht][r]);
    }
  }
  if (t < 64) {
#pragma unroll
    for (int s = 0; s < 11; ++s) {
#pragma unroll
      for (int off = 32; off; off >>= 1) csA[s] += __shfl_xor(csA[s], off);
    }
    if (lane == 0) {
#pragma unroll
      for (int s = 0; s < 11; ++s) atomicAdd(&colsum[b*16 + s], csA[s]);
    }
  }
}

// ---------------- gx = (updates / colsum) @ w_i  (k-split, block 384) ------
__global__ __launch_bounds__(384)
void k_gx(const float* __restrict__ updates, const float* __restrict__ colsum,
          const u16* __restrict__ wib, float* __restrict__ gx) {
  __shared__ float xn[256];
  __shared__ float part[4][768];
  int row = blockIdx.x, t = threadIdx.x;
  if (t < 256) {
    float inv = 1.f / colsum[(row/11)*16 + (row%11)];
    xn[t] = updates[row*256 + t] * inv;
  }
  __syncthreads();
  int tc = t % 96, kg = t / 96;
  float a[8] = {};
#pragma unroll 4
  for (int kk = 0; kk < 64; ++kk) {
    int k = kg*64 + kk;
    float xv = xn[k];
    u16x8 wv = *(const u16x8*)(wib + k*768 + tc*8);
#pragma unroll
    for (int j = 0; j < 8; ++j) a[j] += xv * bf2f(wv[j]);
  }
  *(float4*)&part[kg][tc*8]     = make_float4(a[0], a[1], a[2], a[3]);
  *(float4*)&part[kg][tc*8 + 4] = make_float4(a[4], a[5], a[6], a[7]);
  __syncthreads();
#pragma unroll
  for (int c = t; c < 768; c += 384) {
    float s = part[0][c] + part[1][c] + part[2][c] + part[3][c];
    gx[row*768 + c] = s;
  }
}

// ---------------- GRU (block 512, k-split, bf16 wh) ------------------------
__global__ __launch_bounds__(512)
void k_gru(const float* __restrict__ gx, const u16* __restrict__ whb,
           const float* __restrict__ gb, float* __restrict__ slots) {
  __shared__ float h[256], rh[256], zv[256];
  __shared__ float part[4096];
  int b = blockIdx.x, t = threadIdx.x;
  if (t < 256) h[t] = 0.f;
  __syncthreads();
  for (int step = 0; step < 11; ++step) {
    int row = b*11 + step;
    {
      int tc = t & 63, kg = t >> 6;
      float a[8] = {};
#pragma unroll 8
      for (int kk = 0; kk < 32; ++kk) {
        int k = kg*32 + kk;
        float xv = h[k];
        u16x8 wv = *(const u16x8*)(whb + k*768 + tc*8);
#pragma unroll
        for (int j = 0; j < 8; ++j) a[j] += xv * bf2f(wv[j]);
      }
      *(float4*)&part[kg*512 + tc*8]     = make_float4(a[0], a[1], a[2], a[3]);
      *(float4*)&part[kg*512 + tc*8 + 4] = make_float4(a[4], a[5], a[6], a[7]);
    }
    __syncthreads();
    {
      int c = t;
      float s = gx[row*768 + c] + gb[c];
#pragma unroll
      for (int g = 0; g < 8; ++g) s += part[g*512 + c];
      float sg = 1.f / (1.f + __expf(-s));
      if (c < 256) zv[c] = sg;
      else         rh[c - 256] = sg * h[c - 256];
    }
    __syncthreads();
    {
      int tc = t & 31, kg = t >> 5;
      float a[8] = {};
#pragma unroll 8
      for (int kk = 0; kk < 16; ++kk) {
        int k = kg*16 + kk;
        float xv = rh[k];
        u16x8 wv = *(const u16x8*)(whb + k*768 + 512 + tc*8);
#pragma unroll
        for (int j = 0; j < 8; ++j) a[j] += xv * bf2f(wv[j]);
      }
      *(float4*)&part[kg*256 + tc*8]     = make_float4(a[0], a[1], a[2], a[3]);
      *(float4*)&part[kg*256 + tc*8 + 4] = make_float4(a[4], a[5], a[6], a[7]);
    }
    __syncthreads();
    if (t < 256) {
      int c = t;
      float s = gx[row*768 + 512 + c] + gb[512 + c];
#pragma unroll
      for (int g = 0; g < 16; ++g) s += part[g*256 + c];
      float av = tanhf(s);
      float hn = (1.f - zv[c])*h[c] + zv[c]*av;
      h[c] = hn;
      slots[row*256 + c] = hn;
    }
    __syncthreads();
  }
}

// ---------------- MLP (k-split, bf16 w1/w2) --------------------------------
__global__ __launch_bounds__(256)
void k_mlp(float* __restrict__ slots, const float* __restrict__ sc,
           const float* __restrict__ of, const u16* __restrict__ w1b,
           const float* __restrict__ b1, const u16* __restrict__ w2b,
           const float* __restrict__ b2, float* __restrict__ out2) {
  __shared__ float xn[256];
  __shared__ float hid[512];
  __shared__ float red[8];
  __shared__ float part[2048];
  int row = blockIdx.x, t = threadIdx.x;
  float v = slots[row*256 + t];
  float s1 = v, s2 = v*v;
#pragma unroll
  for (int off = 32; off; off >>= 1) { s1 += __shfl_xor(s1, off); s2 += __shfl_xor(s2, off); }
  int w = t >> 6;
  if ((t & 63) == 0) { red[w*2] = s1; red[w*2+1] = s2; }
  __syncthreads();
  float a1s = red[0] + red[2] + red[4] + red[6];
  float a2s = red[1] + red[3] + red[5] + red[7];
  float mu = a1s * (1.f/256.f);
  float rs = rsqrtf(a2s * (1.f/256.f) - mu*mu + 1e-5f);
  xn[t] = (v - mu) * rs * sc[t] + of[t];
  __syncthreads();
  {
    int tc = t & 63, kg = t >> 6;
    float a[8] = {};
#pragma unroll 4
    for (int kk = 0; kk < 64; ++kk) {
      int k = kg*64 + kk;
      float xv = xn[k];
      u16x8 wv = *(const u16x8*)(w1b + k*512 + tc*8);
#pragma unroll
      for (int j = 0; j < 8; ++j) a[j] += xv * bf2f(wv[j]);
    }
    *(float4*)&part[kg*512 + tc*8]     = make_float4(a[0], a[1], a[2], a[3]);
    *(float4*)&part[kg*512 + tc*8 + 4] = make_float4(a[4], a[5], a[6], a[7]);
  }
  __syncthreads();
#pragma unroll
  for (int c = t; c < 512; c += 256) {
    float s = b1[c];
#pragma unroll
    for (int g = 0; g < 4; ++g) s += part[g*512 + c];
    hid[c] = fmaxf(s, 0.f);
  }
  __syncthreads();
  {
    int tc = t & 31, kg = t >> 5;
    float a[8] = {};
#pragma unroll 4
    for (int kk = 0; kk < 64; ++kk) {
      int k = kg*64 + kk;
      float xv = hid[k];
      u16x8 wv = *(const u16x8*)(w2b + k*256 + tc*8);
#pragma unroll
      for (int j = 0; j < 8; ++j) a[j] += xv * bf2f(wv[j]);
    }
    *(float4*)&part[kg*256 + tc*8]     = make_float4(a[0], a[1], a[2], a[3]);
    *(float4*)&part[kg*256 + tc*8 + 4] = make_float4(a[4], a[5], a[6], a[7]);
  }
  __syncthreads();
  {
    float s = v + b2[t];
#pragma unroll
    for (int g = 0; g < 8; ++g) s += part[g*256 + t];
    slots[row*256 + t] = s;
    if (out2) out2[row*256 + t] = s;
  }
}

extern "C" void kernel_launch(void* const* d_in, const int* in_sizes, int n_in,
                              void* d_out, int out_size, void* d_ws, size_t ws_size,
                              hipStream_t stream) {
  (void)in_sizes; (void)n_in; (void)out_size; (void)ws_size;
  const float* inputs = (const float*)d_in[0];
  const float* noise  = (const float*)d_in[1];
  const float* lnin_s = (const float*)d_in[2];
  const float* lnin_o = (const float*)d_in[3];
  const float* lnsl_s = (const float*)d_in[4];
  const float* lnsl_o = (const float*)d_in[5];
  const float* lnml_s = (const float*)d_in[6];
  const float* lnml_o = (const float*)d_in[7];
  const float* smu    = (const float*)d_in[8];
  const float* sls    = (const float*)d_in[9];
  const float* Wq     = (const float*)d_in[10];
  const float* Wk     = (const float*)d_in[11];
  const float* Wv     = (const float*)d_in[12];
  const float* gwi    = (const float*)d_in[13];
  const float* gwh    = (const float*)d_in[14];
  const float* gb     = (const float*)d_in[15];
  const float* w1     = (const float*)d_in[16];
  const float* b1     = (const float*)d_in[17];
  const float* w2     = (const float*)d_in[18];
  const float* b2     = (const float*)d_in[19];

  // ---- workspace layout: high-water 143,230,976 B (round-3-proven arena) ----
  char* ws = (char*)d_ws;
  u16*    kv      = (u16*)(ws);
  u16*    wT      = (u16*)(ws + 134217728);              // scratch region (ex-attn)
  float*  slots   = (float*)(ws + 139984896);
  float*  updates = (float*)(ws + 140345344);
  float*  gx      = (float*)(ws + 140705792);
  float*  q       = (float*)(ws + 140705792);            // aliases gx (q dead before k_gx)
  float*  colsum  = (float*)(ws + 141787136);
  u16*    wqb     = (u16*)(ws + 141789184);
  u16*    wib     = (u16*)(ws + 141920256);
  u16*    whb     = (u16*)(ws + 142313472);
  u16*    w1b     = (u16*)(ws + 142706688);
  u16*    w2b     = (u16*)(ws + 142968832);

  k_cvt_w     <<<32,    256, 0, stream>>>(Wk, Wv, wT);
  k_cvt_all   <<<2816,  256, 0, stream>>>(Wq, gwi, gwh, w1, w2, wqb, wib, whb, w1b, w2b);
  k_slots_init<<<352,   256, 0, stream>>>(noise, smu, sls, slots);
  k_gemm_kv   <<<4096,  256, 0, stream>>>(inputs, lnin_s, lnin_o, wT, kv);

  for (int it = 0; it < 3; ++it) {
    k_q_ln    <<<352, 256, 0, stream>>>(slots, lnsl_s, lnsl_o, wqb, q, updates, colsum);
    k_attn_up <<<dim3(16, 32), 256, 0, stream>>>(kv, q, updates, colsum);
    k_gx      <<<352, 384, 0, stream>>>(updates, colsum, wib, gx);
    k_gru     <<<32,  512, 0, stream>>>(gx, whb, gb, slots);
    k_mlp     <<<352, 256, 0, stream>>>(slots, lnml_s, lnml_o, w1b, b1, w2b, b2,
                                        (it == 2) ? (float*)d_out : nullptr);
  }
}

// Round 8
// 662.887 us; speedup vs baseline: 1.0512x; 1.0512x over previous
//
#include <hip/hip_runtime.h>

typedef unsigned short u16;
typedef __bf16 bf16x8 __attribute__((ext_vector_type(8)));
typedef float  f32x4  __attribute__((ext_vector_type(4)));
typedef unsigned short u16x8 __attribute__((ext_vector_type(8)));

union U8cast { u16x8 u; bf16x8 b; };

#define NB 32
#define NN 4096
#define ND 256
#define NS 11
#define NH 256
#define NM 512

__device__ __forceinline__ u16 f2bf(float f) {
  unsigned u = __float_as_uint(f);
  u += 0x7FFF + ((u >> 16) & 1);      // RNE; inputs are finite
  return (u16)(u >> 16);
}
__device__ __forceinline__ float bf2f(u16 h) {
  return __uint_as_float(((unsigned)h) << 16);
}

// ---------------- per-row mean / rstd of inputs (one wave per row) ----------
__global__ void k_stats(const float* __restrict__ x, float2* __restrict__ mu_rs) {
  int lane = threadIdx.x & 63;
  int wid  = threadIdx.x >> 6;
  int row  = blockIdx.x * 4 + wid;
  float4 v = *(const float4*)(x + (size_t)row * 256 + lane * 4);
  float s1 = v.x + v.y + v.z + v.w;
  float s2 = v.x*v.x + v.y*v.y + v.z*v.z + v.w*v.w;
#pragma unroll
  for (int off = 32; off; off >>= 1) { s1 += __shfl_xor(s1, off); s2 += __shfl_xor(s2, off); }
  if (lane == 0) {
    float mu  = s1 * (1.f/256.f);
    float var = s2 * (1.f/256.f) - mu*mu;
    mu_rs[row] = make_float2(mu, rsqrtf(var + 1e-5f));
  }
}

// ---------------- Wk|Wv -> transposed bf16 wT[512][256] (LDS transpose) ----
__global__ __launch_bounds__(256)
void k_cvt_w(const float* __restrict__ Wk, const float* __restrict__ Wv,
             u16* __restrict__ wT) {
  __shared__ float Lt[64][65];
  int bx = blockIdx.x;              // 32 blocks: 4 k-tiles x 8 c-tiles
  int kt = bx & 3, ct = bx >> 2;
  int k0 = kt * 64, c0 = ct * 64;
  const float* src = (c0 < 256) ? Wk : Wv;
  int c0m = c0 & 255;
  int t = threadIdx.x;
  int kr = t >> 2, part = t & 3;
  const float* sp = src + (size_t)(k0 + kr) * 256 + c0m + part * 16;
#pragma unroll
  for (int g = 0; g < 4; ++g) {
    float4 v = *(const float4*)(sp + g * 4);
    Lt[kr][part*16 + g*4 + 0] = v.x;
    Lt[kr][part*16 + g*4 + 1] = v.y;
    Lt[kr][part*16 + g*4 + 2] = v.z;
    Lt[kr][part*16 + g*4 + 3] = v.w;
  }
  __syncthreads();
  int cr = t >> 2;
  u16* wp = wT + (size_t)(c0 + cr) * 256 + k0 + part * 16;
#pragma unroll
  for (int g = 0; g < 2; ++g) {
    u16x8 o;
#pragma unroll
    for (int j = 0; j < 8; ++j) o[j] = f2bf(Lt[part*16 + g*8 + j][cr]);
    *(u16x8*)(wp + g * 8) = o;
  }
}

// ---------------- convert all small-matmul weights to bf16 -----------------
__global__ void k_cvt_all(const float* __restrict__ Wq, const float* __restrict__ wi,
                          const float* __restrict__ wh, const float* __restrict__ w1,
                          const float* __restrict__ w2, u16* __restrict__ wqb,
                          u16* __restrict__ wib, u16* __restrict__ whb,
                          u16* __restrict__ w1b, u16* __restrict__ w2b) {
  int idx = blockIdx.x * 256 + threadIdx.x;
  if      (idx < 65536)  wqb[idx]          = f2bf(Wq[idx]);
  else if (idx < 262144) wib[idx - 65536]  = f2bf(wi[idx - 65536]);
  else if (idx < 458752) whb[idx - 262144] = f2bf(wh[idx - 262144]);
  else if (idx < 589824) w1b[idx - 458752] = f2bf(w1[idx - 458752]);
  else                   w2b[idx - 589824] = f2bf(w2[idx - 589824]);
}

// ---------------- slots init ----------------------------------------------
__global__ void k_slots_init(const float* __restrict__ noise, const float* __restrict__ mu,
                             const float* __restrict__ ls, float* __restrict__ slots) {
  int row = blockIdx.x, t = threadIdx.x;
  slots[row*256 + t] = mu[t] + expf(ls[t]) * noise[row*256 + t];
}

// ---------------- fused LN + bf16 MFMA GEMM: kv = LN(x) @ [Wk|Wv] ----------
// Round-4 proven body (mu_rs-based LN, 128x128 tile, 4 blocks/CU) + round-7
// proven XCD swizzle (4 col-tiles of a row-tile adjacent on one XCD -> x
// HBM-fetched ~once per row-tile).
__global__ __launch_bounds__(256)
void k_gemm_kv(const float* __restrict__ x, const float2* __restrict__ mu_rs,
               const float* __restrict__ lnsc, const float* __restrict__ lnof,
               const u16* __restrict__ wT, u16* __restrict__ kv) {
  __shared__ __align__(16) u16 Al[128][72];
  __shared__ __align__(16) u16 Bl[128][72];
  __shared__ float scl[256], ofl[256];
  int t = threadIdx.x;
  scl[t] = lnsc[t]; ofl[t] = lnof[t];

  int bid = blockIdx.x;                    // 4096 blocks
  int xcd  = bid & 7;
  int slot = bid >> 3;                     // 0..511 per XCD
  int colt = slot & 3;                     // 4 col-tiles adjacent per row-tile
  int rowt = xcd * 128 + (slot >> 2);      // 0..1023
  int row0 = rowt * 128;
  int col0 = colt * 128;

  int srow = t >> 1, shalf = t & 1;
  float2 mr = mu_rs[row0 + srow];
  int lane = t & 63, w = t >> 6;
  int wm = (w & 1) * 64, wn = (w >> 1) * 64;
  int fr = lane & 15;
  int kq = (lane >> 4) * 8;
  f32x4 acc[4][4] = {};
  const float* xp0 = x + (size_t)(row0 + srow) * 256 + shalf * 32;
  for (int kc = 0; kc < 256; kc += 64) {
    __syncthreads();
    { // stage A with LN applied, cast to bf16
      const float* xp = xp0 + kc;
#pragma unroll
      for (int g = 0; g < 4; ++g) {
        float4 f0 = *(const float4*)(xp + g*8);
        float4 f1 = *(const float4*)(xp + g*8 + 4);
        int kb = kc + shalf*32 + g*8;
        bf16x8 o;
        o[0] = (__bf16)((f0.x - mr.x) * (mr.y * scl[kb+0]) + ofl[kb+0]);
        o[1] = (__bf16)((f0.y - mr.x) * (mr.y * scl[kb+1]) + ofl[kb+1]);
        o[2] = (__bf16)((f0.z - mr.x) * (mr.y * scl[kb+2]) + ofl[kb+2]);
        o[3] = (__bf16)((f0.w - mr.x) * (mr.y * scl[kb+3]) + ofl[kb+3]);
        o[4] = (__bf16)((f1.x - mr.x) * (mr.y * scl[kb+4]) + ofl[kb+4]);
        o[5] = (__bf16)((f1.y - mr.x) * (mr.y * scl[kb+5]) + ofl[kb+5]);
        o[6] = (__bf16)((f1.z - mr.x) * (mr.y * scl[kb+6]) + ofl[kb+6]);
        o[7] = (__bf16)((f1.w - mr.x) * (mr.y * scl[kb+7]) + ofl[kb+7]);
        *(bf16x8*)&Al[srow][shalf*32 + g*8] = o;
      }
      const u16* wp = wT + (size_t)(col0 + srow) * 256 + kc + shalf*32;
#pragma unroll
      for (int g = 0; g < 4; ++g)
        *(u16x8*)&Bl[srow][shalf*32 + g*8] = *(const u16x8*)(wp + g*8);
    }
    __syncthreads();
#pragma unroll
    for (int ks = 0; ks < 2; ++ks) {
      int kk = ks*32 + kq;
      bf16x8 af[4], bfr[4];
#pragma unroll
      for (int i = 0; i < 4; ++i) af[i] = *(const bf16x8*)&Al[wm + i*16 + fr][kk];
#pragma unroll
      for (int i = 0; i < 4; ++i) bfr[i] = *(const bf16x8*)&Bl[wn + i*16 + fr][kk];
#pragma unroll
      for (int im = 0; im < 4; ++im)
#pragma unroll
        for (int in = 0; in < 4; ++in)
          acc[im][in] = __builtin_amdgcn_mfma_f32_16x16x32_bf16(af[im], bfr[in], acc[im][in], 0, 0, 0);
    }
  }
  // epilogue: D mapping col=lane&15, row=(lane>>4)*4+r
  int r4 = (lane >> 4) * 4;
#pragma unroll
  for (int im = 0; im < 4; ++im)
#pragma unroll
    for (int in = 0; in < 4; ++in) {
      int gcol = col0 + wn + in*16 + fr;
#pragma unroll
      for (int r = 0; r < 4; ++r) {
        int grow = row0 + wm + im*16 + r4 + r;
        kv[(size_t)grow * 512 + gcol] = f2bf(acc[im][in][r]);
      }
    }
}

// ---------------- q = LN(slots) @ Wq * H^-0.5 (k-split); zero updates ------
__global__ __launch_bounds__(256)
void k_q_ln(const float* __restrict__ slots, const float* __restrict__ sc,
            const float* __restrict__ of, const u16* __restrict__ wqb,
            float* __restrict__ q, float* __restrict__ updates,
            float* __restrict__ colsum) {
  __shared__ float xn[256];
  __shared__ float red[8];
  __shared__ float part[8][256];
  int row = blockIdx.x, t = threadIdx.x;
  float v = slots[row*256 + t];
  float s1 = v, s2 = v*v;
#pragma unroll
  for (int off = 32; off; off >>= 1) { s1 += __shfl_xor(s1, off); s2 += __shfl_xor(s2, off); }
  int w = t >> 6;
  if ((t & 63) == 0) { red[w*2] = s1; red[w*2+1] = s2; }
  __syncthreads();
  float a1 = red[0] + red[2] + red[4] + red[6];
  float a2 = red[1] + red[3] + red[5] + red[7];
  float mu = a1 * (1.f/256.f);
  float rs = rsqrtf(a2 * (1.f/256.f) - mu*mu + 1e-5f);
  xn[t] = (v - mu) * rs * sc[t] + of[t];
  updates[row*256 + t] = 0.f;
  if (t == 0) colsum[(row/11)*16 + (row%11)] = 0.f;
  __syncthreads();
  int tc = t & 31, kg = t >> 5;
  float a[8] = {};
#pragma unroll 8
  for (int kk = 0; kk < 32; ++kk) {
    int k = kg*32 + kk;
    float xv = xn[k];
    u16x8 wv = *(const u16x8*)(wqb + k*256 + tc*8);
#pragma unroll
    for (int j = 0; j < 8; ++j) a[j] += xv * bf2f(wv[j]);
  }
  *(float4*)&part[kg][tc*8]     = make_float4(a[0], a[1], a[2], a[3]);
  *(float4*)&part[kg][tc*8 + 4] = make_float4(a[4], a[5], a[6], a[7]);
  __syncthreads();
  float s = 0.f;
#pragma unroll
  for (int g = 0; g < 8; ++g) s += part[g][t];
  q[row*256 + t] = s * 0.0625f;
}

// ---------------- FUSED attn: logits->softmax->P, updates += P^T @ vf ------
__global__ __launch_bounds__(256)
void k_attn_up(const u16* __restrict__ kv, const float* __restrict__ qg,
               float* __restrict__ updates, float* __restrict__ colsum) {
  __shared__ __align__(16) u16 kfL[64][264];
  __shared__ __align__(16) u16 vfL[64][256];   // chunk-swizzled: col = h ^ (((n>>3)&3)*16)
  __shared__ __align__(16) u16 qTL[16][264];
  __shared__ __align__(16) u16 PTL[16][72];
  __shared__ float Lg[64][17];
  int t = threadIdx.x;
  int b = blockIdx.y;
  int nb0 = blockIdx.x * 256;
  int lane = t & 63, w = t >> 6;
  int fr = lane & 15, kq = lane >> 4;

#pragma unroll
  for (int i = t; i < 512; i += 256) {
    int s = i >> 5, k0 = (i & 31) * 8;
    u16x8 o;
    if (s < 11) {
      const float* qp = qg + (size_t)b*2816 + s*256 + k0;
#pragma unroll
      for (int j = 0; j < 8; ++j) o[j] = f2bf(qp[j]);
    } else {
#pragma unroll
      for (int j = 0; j < 8; ++j) o[j] = 0;
    }
    *(u16x8*)&qTL[s][k0] = o;
  }
  for (int i = t; i < 16*72; i += 256) ((u16*)PTL)[i] = 0;

  f32x4 accU[4] = {};
  float csA[11];
#pragma unroll
  for (int s = 0; s < 11; ++s) csA[s] = 0.f;

  for (int c = 0; c < 4; ++c) {
    int n0 = nb0 + c*64;
    __syncthreads();
    {
      int hc = (t & 31) * 8;
#pragma unroll
      for (int nr = 0; nr < 8; ++nr) {
        int n = nr*8 + (t >> 5);
        size_t base = ((size_t)b*4096 + n0 + n) * 512;
        u16x8 kvk = *(const u16x8*)(kv + base + hc);
        *(u16x8*)&kfL[n][hc] = kvk;
        u16x8 kvv = *(const u16x8*)(kv + base + 256 + hc);
        *(u16x8*)&vfL[n][hc ^ (((n >> 3) & 3) * 16)] = kvv;
      }
    }
    __syncthreads();
    {
      f32x4 aL = {};
#pragma unroll
      for (int kc = 0; kc < 256; kc += 32) {
        bf16x8 af = *(const bf16x8*)&kfL[w*16 + fr][kc + kq*8];
        bf16x8 bq = *(const bf16x8*)&qTL[fr][kc + kq*8];
        aL = __builtin_amdgcn_mfma_f32_16x16x32_bf16(af, bq, aL, 0, 0, 0);
      }
#pragma unroll
      for (int r = 0; r < 4; ++r)
        Lg[w*16 + kq*4 + r][fr] = aL[r];
    }
    __syncthreads();
    if (t < 64) {
      float p[11];
#pragma unroll
      for (int s = 0; s < 11; ++s) p[s] = Lg[t][s];
      float m = p[0];
#pragma unroll
      for (int s = 1; s < 11; ++s) m = fmaxf(m, p[s]);
      float Z = 0.f;
#pragma unroll
      for (int s = 0; s < 11; ++s) { p[s] = __expf(p[s] - m); Z += p[s]; }
      float iz = 1.f / Z;
#pragma unroll
      for (int s = 0; s < 11; ++s) {
        u16 pb = f2bf(p[s]*iz + 1e-8f);
        csA[s] += bf2f(pb);
        PTL[s][t] = pb;
      }
    }
    __syncthreads();
#pragma unroll
    for (int ht = 0; ht < 4; ++ht) {
      int h = w*64 + ht*16 + fr;
#pragma unroll
      for (int kc = 0; kc < 64; kc += 32) {
        bf16x8 aP = *(const bf16x8*)&PTL[fr][kc + kq*8];
        U8cast bv;
#pragma unroll
        for (int j = 0; j < 8; ++j) {
          int k = kc + kq*8 + j;
          bv.u[j] = vfL[k][h ^ (((k >> 3) & 3) * 16)];
        }
        accU[ht] = __builtin_amdgcn_mfma_f32_16x16x32_bf16(aP, bv.b, accU[ht], 0, 0, 0);
      }
    }
  }
#pragma unroll
  for (int ht = 0; ht < 4; ++ht) {
    int h = w*64 + ht*16 + fr;
#pragma unroll
    for (int r = 0; r < 4; ++r) {
      int s = kq*4 + r;
      if (s < 11)
        atomicAdd(&updates[((size_t)b*11 + s)*256 + h], accU[ht][r]);
    }
  }
  if (t < 64) {
#pragma unroll
    for (int s = 0; s < 11; ++s) {
#pragma unroll
      for (int off = 32; off; off >>= 1) csA[s] += __shfl_xor(csA[s], off);
    }
    if (lane == 0) {
#pragma unroll
      for (int s = 0; s < 11; ++s) atomicAdd(&colsum[b*16 + s], csA[s]);
    }
  }
}

// ---------------- gx = (updates / colsum) @ w_i  (k-split, block 384) ------
__global__ __launch_bounds__(384)
void k_gx(const float* __restrict__ updates, const float* __restrict__ colsum,
          const u16* __restrict__ wib, float* __restrict__ gx) {
  __shared__ float xn[256];
  __shared__ float part[4][768];
  int row = blockIdx.x, t = threadIdx.x;
  if (t < 256) {
    float inv = 1.f / colsum[(row/11)*16 + (row%11)];
    xn[t] = updates[row*256 + t] * inv;
  }
  __syncthreads();
  int tc = t % 96, kg = t / 96;
  float a[8] = {};
#pragma unroll 4
  for (int kk = 0; kk < 64; ++kk) {
    int k = kg*64 + kk;
    float xv = xn[k];
    u16x8 wv = *(const u16x8*)(wib + k*768 + tc*8);
#pragma unroll
    for (int j = 0; j < 8; ++j) a[j] += xv * bf2f(wv[j]);
  }
  *(float4*)&part[kg][tc*8]     = make_float4(a[0], a[1], a[2], a[3]);
  *(float4*)&part[kg][tc*8 + 4] = make_float4(a[4], a[5], a[6], a[7]);
  __syncthreads();
#pragma unroll
  for (int c = t; c < 768; c += 384) {
    float s = part[0][c] + part[1][c] + part[2][c] + part[3][c];
    gx[row*768 + c] = s;
  }
}

// ---------------- GRU (block 512, k-split, bf16 wh) ------------------------
__global__ __launch_bounds__(512)
void k_gru(const float* __restrict__ gx, const u16* __restrict__ whb,
           const float* __restrict__ gb, float* __restrict__ slots) {
  __shared__ float h[256], rh[256], zv[256];
  __shared__ float part[4096];
  int b = blockIdx.x, t = threadIdx.x;
  if (t < 256) h[t] = 0.f;
  __syncthreads();
  for (int step = 0; step < 11; ++step) {
    int row = b*11 + step;
    {
      int tc = t & 63, kg = t >> 6;
      float a[8] = {};
#pragma unroll 8
      for (int kk = 0; kk < 32; ++kk) {
        int k = kg*32 + kk;
        float xv = h[k];
        u16x8 wv = *(const u16x8*)(whb + k*768 + tc*8);
#pragma unroll
        for (int j = 0; j < 8; ++j) a[j] += xv * bf2f(wv[j]);
      }
      *(float4*)&part[kg*512 + tc*8]     = make_float4(a[0], a[1], a[2], a[3]);
      *(float4*)&part[kg*512 + tc*8 + 4] = make_float4(a[4], a[5], a[6], a[7]);
    }
    __syncthreads();
    {
      int c = t;
      float s = gx[row*768 + c] + gb[c];
#pragma unroll
      for (int g = 0; g < 8; ++g) s += part[g*512 + c];
      float sg = 1.f / (1.f + __expf(-s));
      if (c < 256) zv[c] = sg;
      else         rh[c - 256] = sg * h[c - 256];
    }
    __syncthreads();
    {
      int tc = t & 31, kg = t >> 5;
      float a[8] = {};
#pragma unroll 8
      for (int kk = 0; kk < 16; ++kk) {
        int k = kg*16 + kk;
        float xv = rh[k];
        u16x8 wv = *(const u16x8*)(whb + k*768 + 512 + tc*8);
#pragma unroll
        for (int j = 0; j < 8; ++j) a[j] += xv * bf2f(wv[j]);
      }
      *(float4*)&part[kg*256 + tc*8]     = make_float4(a[0], a[1], a[2], a[3]);
      *(float4*)&part[kg*256 + tc*8 + 4] = make_float4(a[4], a[5], a[6], a[7]);
    }
    __syncthreads();
    if (t < 256) {
      int c = t;
      float s = gx[row*768 + 512 + c] + gb[512 + c];
#pragma unroll
      for (int g = 0; g < 16; ++g) s += part[g*256 + c];
      float av = tanhf(s);
      float hn = (1.f - zv[c])*h[c] + zv[c]*av;
      h[c] = hn;
      slots[row*256 + c] = hn;
    }
    __syncthreads();
  }
}

// ---------------- MLP (k-split, bf16 w1/w2) --------------------------------
__global__ __launch_bounds__(256)
void k_mlp(float* __restrict__ slots, const float* __restrict__ sc,
           const float* __restrict__ of, const u16* __restrict__ w1b,
           const float* __restrict__ b1, const u16* __restrict__ w2b,
           const float* __restrict__ b2, float* __restrict__ out2) {
  __shared__ float xn[256];
  __shared__ float hid[512];
  __shared__ float red[8];
  __shared__ float part[2048];
  int row = blockIdx.x, t = threadIdx.x;
  float v = slots[row*256 + t];
  float s1 = v, s2 = v*v;
#pragma unroll
  for (int off = 32; off; off >>= 1) { s1 += __shfl_xor(s1, off); s2 += __shfl_xor(s2, off); }
  int w = t >> 6;
  if ((t & 63) == 0) { red[w*2] = s1; red[w*2+1] = s2; }
  __syncthreads();
  float a1s = red[0] + red[2] + red[4] + red[6];
  float a2s = red[1] + red[3] + red[5] + red[7];
  float mu = a1s * (1.f/256.f);
  float rs = rsqrtf(a2s * (1.f/256.f) - mu*mu + 1e-5f);
  xn[t] = (v - mu) * rs * sc[t] + of[t];
  __syncthreads();
  {
    int tc = t & 63, kg = t >> 6;
    float a[8] = {};
#pragma unroll 4
    for (int kk = 0; kk < 64; ++kk) {
      int k = kg*64 + kk;
      float xv = xn[k];
      u16x8 wv = *(const u16x8*)(w1b + k*512 + tc*8);
#pragma unroll
      for (int j = 0; j < 8; ++j) a[j] += xv * bf2f(wv[j]);
    }
    *(float4*)&part[kg*512 + tc*8]     = make_float4(a[0], a[1], a[2], a[3]);
    *(float4*)&part[kg*512 + tc*8 + 4] = make_float4(a[4], a[5], a[6], a[7]);
  }
  __syncthreads();
#pragma unroll
  for (int c = t; c < 512; c += 256) {
    float s = b1[c];
#pragma unroll
    for (int g = 0; g < 4; ++g) s += part[g*512 + c];
    hid[c] = fmaxf(s, 0.f);
  }
  __syncthreads();
  {
    int tc = t & 31, kg = t >> 5;
    float a[8] = {};
#pragma unroll 4
    for (int kk = 0; kk < 64; ++kk) {
      int k = kg*64 + kk;
      float xv = hid[k];
      u16x8 wv = *(const u16x8*)(w2b + k*256 + tc*8);
#pragma unroll
      for (int j = 0; j < 8; ++j) a[j] += xv * bf2f(wv[j]);
    }
    *(float4*)&part[kg*256 + tc*8]     = make_float4(a[0], a[1], a[2], a[3]);
    *(float4*)&part[kg*256 + tc*8 + 4] = make_float4(a[4], a[5], a[6], a[7]);
  }
  __syncthreads();
  {
    float s = v + b2[t];
#pragma unroll
    for (int g = 0; g < 8; ++g) s += part[g*256 + t];
    slots[row*256 + t] = s;
    if (out2) out2[row*256 + t] = s;
  }
}

extern "C" void kernel_launch(void* const* d_in, const int* in_sizes, int n_in,
                              void* d_out, int out_size, void* d_ws, size_t ws_size,
                              hipStream_t stream) {
  (void)in_sizes; (void)n_in; (void)out_size; (void)ws_size;
  const float* inputs = (const float*)d_in[0];
  const float* noise  = (const float*)d_in[1];
  const float* lnin_s = (const float*)d_in[2];
  const float* lnin_o = (const float*)d_in[3];
  const float* lnsl_s = (const float*)d_in[4];
  const float* lnsl_o = (const float*)d_in[5];
  const float* lnml_s = (const float*)d_in[6];
  const float* lnml_o = (const float*)d_in[7];
  const float* smu    = (const float*)d_in[8];
  const float* sls    = (const float*)d_in[9];
  const float* Wq     = (const float*)d_in[10];
  const float* Wk     = (const float*)d_in[11];
  const float* Wv     = (const float*)d_in[12];
  const float* gwi    = (const float*)d_in[13];
  const float* gwh    = (const float*)d_in[14];
  const float* gb     = (const float*)d_in[15];
  const float* w1     = (const float*)d_in[16];
  const float* b1     = (const float*)d_in[17];
  const float* w2     = (const float*)d_in[18];
  const float* b2     = (const float*)d_in[19];

  // ---- workspace layout: high-water 143,230,976 B (round-3-proven arena) ----
  char* ws = (char*)d_ws;
  u16*    kv      = (u16*)(ws);
  u16*    wT      = (u16*)(ws + 134217728);              // scratch region
  float2* mu_rs   = (float2*)(ws + 134479872);           // after wT (262144 B)
  float*  slots   = (float*)(ws + 139984896);
  float*  updates = (float*)(ws + 140345344);
  float*  gx      = (float*)(ws + 140705792);
  float*  q       = (float*)(ws + 140705792);            // aliases gx (q dead before k_gx)
  float*  colsum  = (float*)(ws + 141787136);
  u16*    wqb     = (u16*)(ws + 141789184);
  u16*    wib     = (u16*)(ws + 141920256);
  u16*    whb     = (u16*)(ws + 142313472);
  u16*    w1b     = (u16*)(ws + 142706688);
  u16*    w2b     = (u16*)(ws + 142968832);

  k_stats     <<<32768, 256, 0, stream>>>(inputs, mu_rs);
  k_cvt_w     <<<32,    256, 0, stream>>>(Wk, Wv, wT);
  k_cvt_all   <<<2816,  256, 0, stream>>>(Wq, gwi, gwh, w1, w2, wqb, wib, whb, w1b, w2b);
  k_slots_init<<<352,   256, 0, stream>>>(noise, smu, sls, slots);
  k_gemm_kv   <<<4096,  256, 0, stream>>>(inputs, mu_rs, lnin_s, lnin_o, wT, kv);

  for (int it = 0; it < 3; ++it) {
    k_q_ln    <<<352, 256, 0, stream>>>(slots, lnsl_s, lnsl_o, wqb, q, updates, colsum);
    k_attn_up <<<dim3(16, 32), 256, 0, stream>>>(kv, q, updates, colsum);
    k_gx      <<<352, 384, 0, stream>>>(updates, colsum, wib, gx);
    k_gru     <<<32,  512, 0, stream>>>(gx, whb, gb, slots);
    k_mlp     <<<352, 256, 0, stream>>>(slots, lnml_s, lnml_o, w1b, b1, w2b, b2,
                                        (it == 2) ? (float*)d_out : nullptr);
  }
}